// Round 21
// baseline (433.465 us; speedup 1.0000x reference)
//
#include <hip/hip_runtime.h>
#include <hip/hip_bf16.h>

using bf16 = __hip_bfloat16;
typedef __attribute__((ext_vector_type(8))) short short8;
typedef __attribute__((ext_vector_type(4))) float f32x4;

// ---------------- helpers ----------------
__device__ __forceinline__ float tof(float v) { return v; }
__device__ __forceinline__ float tof(bf16 v) { return __bfloat162float(v); }
__device__ __forceinline__ float s2f(short s) {
    return __uint_as_float(((unsigned)(unsigned short)s) << 16);
}
__device__ __forceinline__ void storev(float* p, float v) { *p = v; }
__device__ __forceinline__ void storev(bf16* p, float v) { *p = __float2bfloat16(v); }
__device__ __forceinline__ short f2bf_bits(float v) {
    bf16 h = __float2bfloat16(v);
    return *(short*)&h;
}
__device__ __forceinline__ float wsum(float v) {
    #pragma unroll
    for (int o = 32; o > 0; o >>= 1) v += __shfl_xor(v, o);
    return v;
}
__device__ __forceinline__ float wmax(float v) {
    #pragma unroll
    for (int o = 32; o > 0; o >>= 1) v = fmaxf(v, __shfl_xor(v, o));
    return v;
}
// async global->LDS, 16B per lane; LDS dest = wave-uniform base + lane*16
__device__ __forceinline__ void gld_lds16(const void* g, void* l) {
    __builtin_amdgcn_global_load_lds(
        (const __attribute__((address_space(1))) void*)g,
        (__attribute__((address_space(3))) void*)l, 16, 0, 0);
}

// ---------------- weight preconvert: fp32 [Oreal][WLD] -> bf16 [Oalloc][KP], pad 0 ----
__global__ __launch_bounds__(256) void wconv_kernel(
    const float* __restrict__ src, bf16* __restrict__ dst,
    int Oreal, int Oalloc, int K, int KP, int WLD)
{
    const int idx = blockIdx.x * 256 + threadIdx.x;
    if (idx >= Oalloc * KP) return;
    const int o = idx / KP, k = idx % KP;
    float v = (o < Oreal && k < K) ? src[(size_t)o * WLD + k] : 0.f;
    dst[idx] = __float2bfloat16(v);
}

// ---------------- LayerNorm C=192: fp32 [b][192][N] -> bf16 [b][n][192] ----------------
__global__ __launch_bounds__(256) void ln_t_kernel(
    const float* __restrict__ X, const float* __restrict__ w,
    const float* __restrict__ bias, bf16* __restrict__ Y, int N)
{
    __shared__ short ot[128][194];   // row stride 388B: bank stride 97 == 1 (mod 32)
    const int wv = threadIdx.x >> 6, ln_ = threadIdx.x & 63;
    const int pl = wv * 32 + (ln_ & 31);
    const int pg = blockIdx.x * 128 + pl;
    const int b = pg >> 14, n = pg & 16383;       // N = 16384
    const int c0 = (ln_ >> 5) * 96;
    const float* xp = X + ((size_t)b * 192 + c0) * N + n;
    float s = 0.f, s2 = 0.f;
    #pragma unroll
    for (int c = 0; c < 96; c++) { float v = xp[(size_t)c * N]; s += v; s2 += v * v; }
    s += __shfl_xor(s, 32);
    s2 += __shfl_xor(s2, 32);
    const float mean = s * (1.f / 192.f);
    const float rstd = rsqrtf(s2 * (1.f / 192.f) - mean * mean + 1e-5f);
    #pragma unroll
    for (int c = 0; c < 96; c += 2) {
        float v0 = (xp[(size_t)c * N] - mean) * rstd * w[c0 + c] + bias[c0 + c];
        float v1 = (xp[(size_t)(c + 1) * N] - mean) * rstd * w[c0 + c + 1] + bias[c0 + c + 1];
        unsigned u = (unsigned)(unsigned short)f2bf_bits(v0) |
                     ((unsigned)(unsigned short)f2bf_bits(v1) << 16);
        *(unsigned*)&ot[pl][c0 + c] = u;
    }
    __syncthreads();
    bf16* yb = Y + (size_t)blockIdx.x * 128 * 192;
    for (int i = threadIdx.x; i < 12288; i += 256) {
        const int row = i / 96, q = i % 96;
        *(unsigned*)(yb + (size_t)row * 192 + q * 2) = *(const unsigned*)&ot[row][q * 2];
    }
}

// ---- LDS-staged MFMA GEMM, K=192: Y[b][o][n] = W[o][:].X[b][n][:] --------------------
template<int OUTF>
__global__ __launch_bounds__(256) void ldsx_gemm_kernel(
    const bf16* __restrict__ Wb, const bf16* __restrict__ X,
    const float* __restrict__ Rsd, void* __restrict__ Yv,
    int O, int KS, int NROW)
{
    __shared__ short xs[128 * 192];   // 49152 B
    const int OT = gridDim.x, NT = gridDim.y;
    const int orig = blockIdx.x + OT * (blockIdx.y + NT * blockIdx.z);
    const int total = OT * NT * gridDim.z;
    const int qq = total >> 3, rr = total & 7;
    const int xcd = orig & 7, loc = orig >> 3;
    const int nw = (xcd < rr ? xcd * (qq + 1) : rr * (qq + 1) + (xcd - rr) * qq) + loc;
    const int o0 = (nw % OT) * 64;
    const int nbase = ((nw / OT) % NT) * 128;
    const int b = nw / (OT * NT);

    const int wave = threadIdx.x >> 6, lane = threadIdx.x & 63;
    const int arow = lane & 15, kg = lane >> 4;

    const bf16* Xb = X + ((size_t)b * NROW + nbase) * KS;

    short8 wf[6];
    {
        const bf16* wp = Wb + (size_t)(o0 + wave * 16 + arow) * 192 + kg * 8;
        #pragma unroll
        for (int ks = 0; ks < 6; ks++) wf[ks] = *(const short8*)(wp + ks * 32);
    }
    #pragma unroll
    for (int i = 0; i < 12; i++) {
        const int f = (wave * 12 + i) * 64 + lane;
        const int row = f / 24, c = f % 24;
        const int cs = c ^ (row & 7);
        gld_lds16(Xb + (size_t)row * KS + cs * 8,
                  (char*)xs + (size_t)(wave * 12 + i) * 1024);
    }
    __syncthreads();

    f32x4 acc[8];
    #pragma unroll
    for (int s = 0; s < 8; s++) acc[s] = (f32x4){0.f, 0.f, 0.f, 0.f};
    #pragma unroll
    for (int s = 0; s < 8; s++) {
        const int row = s * 16 + arow;
        const char* rb = (const char*)xs + row * 384;
        #pragma unroll
        for (int ks = 0; ks < 6; ks++) {
            const int c = kg + ks * 4;
            short8 xf = *(const short8*)(rb + ((c ^ (row & 7)) << 4));
            acc[s] = __builtin_amdgcn_mfma_f32_16x16x32_bf16(wf[ks], xf, acc[s], 0, 0, 0);
        }
    }

    if constexpr (OUTF == 0) {
        __syncthreads();
        #pragma unroll
        for (int s = 0; s < 8; s++)
            #pragma unroll
            for (int r = 0; r < 4; r++)
                xs[(wave * 16 + kg * 4 + r) * 136 + s * 16 + arow] = f2bf_bits(acc[s][r]);
        __syncthreads();
        bf16* Y = (bf16*)Yv;
        for (int i = threadIdx.x; i < 1024; i += 256) {
            const int row = i >> 4, c8 = (i & 15) * 8;
            const int o = o0 + row;
            if (o < O)
                *(short8*)(Y + ((size_t)b * O + o) * NROW + nbase + c8) =
                    *(const short8*)&xs[row * 136 + c8];
        }
    } else {
        float* fo = (float*)xs;
        __syncthreads();
        #pragma unroll
        for (int s = 0; s < 8; s++)
            #pragma unroll
            for (int r = 0; r < 4; r++)
                fo[(wave * 16 + kg * 4 + r) * 132 + s * 16 + arow] = acc[s][r];
        __syncthreads();
        float* Y = (float*)Yv;
        for (int i = threadIdx.x; i < 8192; i += 256) {
            const int row = i >> 7, col = i & 127;
            const size_t off = ((size_t)b * O + o0 + row) * NROW + nbase + col;
            Y[off] = fo[row * 132 + col] + Rsd[off];
        }
    }
}

// ---- K=512 GEMM (ffn_out): reg-staged ds_write + T14 early-issue; fp32+resid out ----
__global__ __launch_bounds__(256) void ldsx512_gemm_kernel(
    const bf16* __restrict__ Wb, const bf16* __restrict__ X,
    const float* __restrict__ Rsd, float* __restrict__ Y,
    int O, int KS, int NROW)
{
    __shared__ char smem[33792];      // staging: 32768B shorts; epilogue: float[64][132]
    short* xs = (short*)smem;
    float* fo = (float*)smem;
    const int OT = gridDim.x, NT = gridDim.y;
    const int orig = blockIdx.x + OT * (blockIdx.y + NT * blockIdx.z);
    const int total = OT * NT * gridDim.z;
    const int qq = total >> 3, rr = total & 7;
    const int xcd = orig & 7, loc = orig >> 3;
    const int nw = (xcd < rr ? xcd * (qq + 1) : rr * (qq + 1) + (xcd - rr) * qq) + loc;
    const int o0 = (nw % OT) * 64;
    const int nbase = ((nw / OT) % NT) * 128;
    const int b = nw / (OT * NT);

    const int wave = threadIdx.x >> 6, lane = threadIdx.x & 63;
    const int arow = lane & 15, kg = lane >> 4;

    short8 wf[16];
    {
        const bf16* wp = Wb + (size_t)(o0 + wave * 16 + arow) * 512 + kg * 8;
        #pragma unroll
        for (int ks = 0; ks < 16; ks++) wf[ks] = *(const short8*)(wp + ks * 32);
    }
    const bf16* Xb = X + ((size_t)b * NROW + nbase) * KS;

    f32x4 acc[8];
    #pragma unroll
    for (int s = 0; s < 8; s++) acc[s] = (f32x4){0.f, 0.f, 0.f, 0.f};

    // prologue: reg-load + ds_write chunk 0
    {
        short8 xv[8];
        #pragma unroll
        for (int i = 0; i < 8; i++) {
            const int f = (wave * 8 + i) * 64 + lane;
            const int row = f >> 4, c = f & 15;
            const int cs = c ^ (row & 7);
            xv[i] = *(const short8*)(Xb + (size_t)row * KS + cs * 8);
        }
        #pragma unroll
        for (int i = 0; i < 8; i++) {
            const int f = (wave * 8 + i) * 64 + lane;
            *(short8*)((char*)xs + (size_t)f * 16) = xv[i];
        }
    }
    __syncthreads();

    #pragma unroll 1
    for (int kt = 0; kt < 4; kt++) {
        short8 nv[8];
        if (kt < 3) {
            // T14: issue next chunk's loads before computing current chunk
            #pragma unroll
            for (int i = 0; i < 8; i++) {
                const int f = (wave * 8 + i) * 64 + lane;
                const int row = f >> 4, c = f & 15;
                const int cs = c ^ (row & 7);
                nv[i] = *(const short8*)(Xb + (size_t)row * KS + (kt + 1) * 128 + cs * 8);
            }
        }
        #pragma unroll
        for (int s = 0; s < 8; s++) {
            const int row = s * 16 + arow;
            const char* rb = (const char*)xs + row * 256;
            #pragma unroll
            for (int ks = 0; ks < 4; ks++) {
                const int c = kg + ks * 4;
                short8 xf = *(const short8*)(rb + ((c ^ (row & 7)) << 4));
                acc[s] = __builtin_amdgcn_mfma_f32_16x16x32_bf16(wf[kt * 4 + ks], xf, acc[s], 0, 0, 0);
            }
        }
        __syncthreads();            // all reads of xs done
        if (kt < 3) {
            #pragma unroll
            for (int i = 0; i < 8; i++) {
                const int f = (wave * 8 + i) * 64 + lane;
                *(short8*)((char*)xs + (size_t)f * 16) = nv[i];
            }
            __syncthreads();        // buffer ready for next chunk
        }
    }
    #pragma unroll
    for (int s = 0; s < 8; s++)
        #pragma unroll
        for (int r = 0; r < 4; r++)
            fo[(wave * 16 + kg * 4 + r) * 132 + s * 16 + arow] = acc[s][r];
    __syncthreads();
    for (int i = threadIdx.x; i < 8192; i += 256) {
        const int row = i >> 7, col = i & 127;
        const size_t off = ((size_t)b * O + o0 + row) * NROW + nbase + col;
        Y[off] = fo[row * 132 + col] + Rsd[off];
    }
}

// -------- tiled depthwise 3x3 (bf16 planes); SSQ: fused sum-of-squares accumulation ---
template<int SSQ>
__global__ __launch_bounds__(256) void dwconv3_tile_kernel(
    const bf16* __restrict__ X, const float* __restrict__ Wd, bf16* __restrict__ Y,
    int CH, float* __restrict__ ssq)
{
    __shared__ short sm[18][144];   // x0 at col 8; zero halos at 7 and 136
    const int b = blockIdx.z, ch = blockIdx.y;
    const int y0 = blockIdx.x * 16;
    const int tid = threadIdx.x;
    const size_t base = ((size_t)b * CH + ch) * 16384;

    for (int idx = tid; idx < 288; idx += 256) {
        const int r = idx >> 4, xc = idx & 15;
        const int yy = y0 - 1 + r;
        short8 v = {0, 0, 0, 0, 0, 0, 0, 0};
        if (yy >= 0 && yy < 128) v = *(const short8*)(X + base + yy * 128 + xc * 8);
        *(short8*)&sm[r][8 + xc * 8] = v;
    }
    if (tid < 18) { sm[tid][7] = 0; sm[tid][136] = 0; }
    __syncthreads();

    float wv[9];
    #pragma unroll
    for (int i = 0; i < 9; i++) wv[i] = Wd[ch * 9 + i];

    const int ty = tid >> 4, xg = tid & 15;
    float a[8] = {0.f, 0.f, 0.f, 0.f, 0.f, 0.f, 0.f, 0.f};
    #pragma unroll
    for (int dy = 0; dy < 3; dy++) {
        const short* row = &sm[ty + dy][xg * 8];
        short8 pv = *(const short8*)row;
        short8 cv = *(const short8*)(row + 8);
        short8 nv = *(const short8*)(row + 16);
        float u[10];
        u[0] = s2f(((short*)&pv)[7]);
        #pragma unroll
        for (int j = 0; j < 8; j++) u[j + 1] = s2f(((short*)&cv)[j]);
        u[9] = s2f(((short*)&nv)[0]);
        const float wa = wv[dy * 3], wb = wv[dy * 3 + 1], wc = wv[dy * 3 + 2];
        #pragma unroll
        for (int j = 0; j < 8; j++) a[j] += wa * u[j] + wb * u[j + 1] + wc * u[j + 2];
    }
    short8 ov;
    #pragma unroll
    for (int j = 0; j < 8; j++) ((short*)&ov)[j] = f2bf_bits(a[j]);
    *(short8*)(Y + base + (size_t)(y0 + ty) * 128 + xg * 8) = ov;

    if constexpr (SSQ) {
        float s = 0.f;
        #pragma unroll
        for (int j = 0; j < 8; j++) s += a[j] * a[j];
        s = wsum(s);
        __shared__ float red[4];
        if ((tid & 63) == 0) red[tid >> 6] = s;
        __syncthreads();
        if (tid == 0)
            atomicAdd(&ssq[b * 192 + ch], red[0] + red[1] + red[2] + red[3]);
    }
}

// ---- tiled fused dw3(f1)->gelu * dw3(f2) -> GT[b][n][512] ; 4 hc x 8 y x 128 x ------
__global__ __launch_bounds__(256) void dwgelu_tile_kernel(
    const bf16* __restrict__ FB, const float* __restrict__ Wd, bf16* __restrict__ GT)
{
    __shared__ short s1[4][10][152];
    __shared__ short s2[4][10][152];
    const int b = blockIdx.z;
    const int y0 = blockIdx.x * 8;
    const int hc0 = blockIdx.y * 4;
    const int tid = threadIdx.x;

    for (int idx = tid; idx < 640; idx += 256) {
        const int c = idx / 160, rem = idx % 160;
        const int r = rem >> 4, xc = rem & 15;
        const int yy = y0 - 1 + r;
        const int hc = hc0 + c;
        short8 v1 = {0,0,0,0,0,0,0,0}, v2 = v1;
        if (hc < 510 && yy >= 0 && yy < 128) {
            const size_t sp = (size_t)yy * 128 + xc * 8;
            v1 = *(const short8*)(FB + ((size_t)b * 1020 + hc) * 16384 + sp);
            v2 = *(const short8*)(FB + ((size_t)b * 1020 + 510 + hc) * 16384 + sp);
        }
        *(short8*)&s1[c][r][8 + xc * 8] = v1;
        *(short8*)&s2[c][r][8 + xc * 8] = v2;
    }
    if (tid < 40) {
        const int c = tid / 10, r = tid % 10;
        s1[c][r][7] = 0; s1[c][r][136] = 0;
        s2[c][r][7] = 0; s2[c][r][136] = 0;
    }
    __syncthreads();

    const int c = tid >> 6, y2 = (tid >> 4) & 3, xg = tid & 15;
    const int hc = hc0 + c;
    float w1[9], w2[9];
    #pragma unroll
    for (int i = 0; i < 9; i++) {
        w1[i] = (hc < 510) ? Wd[(size_t)hc * 9 + i] : 0.f;
        w2[i] = (hc < 510) ? Wd[(size_t)(510 + hc) * 9 + i] : 0.f;
    }
    float u[4][10], v[4][10];
    #pragma unroll
    for (int r = 0; r < 4; r++) {
        const short* r1 = &s1[c][y2 * 2 + r][xg * 8];
        const short* r2 = &s2[c][y2 * 2 + r][xg * 8];
        short8 pa = *(const short8*)r1;
        short8 ca = *(const short8*)(r1 + 8);
        short8 na = *(const short8*)(r1 + 16);
        short8 pb = *(const short8*)r2;
        short8 cb = *(const short8*)(r2 + 8);
        short8 nb = *(const short8*)(r2 + 16);
        u[r][0] = s2f(((short*)&pa)[7]);
        v[r][0] = s2f(((short*)&pb)[7]);
        #pragma unroll
        for (int j = 0; j < 8; j++) {
            u[r][j + 1] = s2f(((short*)&ca)[j]);
            v[r][j + 1] = s2f(((short*)&cb)[j]);
        }
        u[r][9] = s2f(((short*)&na)[0]);
        v[r][9] = s2f(((short*)&nb)[0]);
    }
    short8 ovr[2];
    #pragma unroll
    for (int t = 0; t < 2; t++) {
        float d1[8] = {0.f,0.f,0.f,0.f,0.f,0.f,0.f,0.f};
        float d2[8] = {0.f,0.f,0.f,0.f,0.f,0.f,0.f,0.f};
        #pragma unroll
        for (int dy = 0; dy < 3; dy++) {
            const int r = t + dy;
            const float a0 = w1[dy * 3], a1 = w1[dy * 3 + 1], a2 = w1[dy * 3 + 2];
            const float b0 = w2[dy * 3], b1 = w2[dy * 3 + 1], b2 = w2[dy * 3 + 2];
            #pragma unroll
            for (int j = 0; j < 8; j++) {
                d1[j] += a0 * u[r][j] + a1 * u[r][j + 1] + a2 * u[r][j + 2];
                d2[j] += b0 * v[r][j] + b1 * v[r][j + 1] + b2 * v[r][j + 2];
            }
        }
        #pragma unroll
        for (int j = 0; j < 8; j++) {
            const float x = d1[j];
            const float z2 = 1.5957691216057308f * (x + 0.044715f * x * x * x);
            const float g = x / (1.f + __expf(-z2));
            ((short*)&ovr[t])[j] = f2bf_bits(g * d2[j]);
        }
    }
    __syncthreads();                 // all s1/s2 reads done; reuse s1 as ot[4][8][136]
    short* ot = &s1[0][0][0];
    {
        const int ob = (c * 8 + y2 * 2) * 136 + xg * 8;
        *(short8*)&ot[ob] = ovr[0];
        *(short8*)&ot[ob + 136] = ovr[1];
    }
    __syncthreads();
    for (int idx = tid; idx < 1024; idx += 256) {
        const int row = idx >> 7, col = idx & 127;
        short v0 = ot[(0 * 8 + row) * 136 + col], v1 = ot[(1 * 8 + row) * 136 + col];
        short v2 = ot[(2 * 8 + row) * 136 + col], v3 = ot[(3 * 8 + row) * 136 + col];
        uint2 pk;
        pk.x = (unsigned)(unsigned short)v0 | ((unsigned)(unsigned short)v1 << 16);
        pk.y = (unsigned)(unsigned short)v2 | ((unsigned)(unsigned short)v3 << 16);
        *(uint2*)(GT + ((size_t)b * 16384 + y0 * 128 + idx) * 512 + hc0) = pk;
    }
}

// ------- gram via MFMA: attn_raw[bh][c][d] += sum_n q[c,n]*k[d,n] over n-chunk --------
__global__ __launch_bounds__(192) void gram_mfma_kernel(
    const bf16* __restrict__ Q, const bf16* __restrict__ K,
    float* __restrict__ attn_raw, int N)
{
    const int b = blockIdx.z, h = blockIdx.y;
    const int n0base = blockIdx.x * 512;
    const int wave = threadIdx.x >> 6, lane = threadIdx.x & 63;
    const int arow = lane & 15, kg = lane >> 4;
    const bf16* Qb = Q + ((size_t)b * 192 + h * 48 + wave * 16 + arow) * N;
    const bf16* Kb = K + ((size_t)b * 192 + h * 48) * N;

    f32x4 acc[3];
    #pragma unroll
    for (int di = 0; di < 3; di++) acc[di] = (f32x4){0.f, 0.f, 0.f, 0.f};

    #pragma unroll 4
    for (int t = 0; t < 16; t++) {
        const int n0 = n0base + t * 32 + kg * 8;
        short8 a = *(const short8*)(Qb + n0);
        #pragma unroll
        for (int di = 0; di < 3; di++) {
            short8 bfr = *(const short8*)(Kb + (size_t)(di * 16 + arow) * N + n0);
            acc[di] = __builtin_amdgcn_mfma_f32_16x16x32_bf16(a, bfr, acc[di], 0, 0, 0);
        }
    }
    float* A = attn_raw + (size_t)(b * 4 + h) * 2304;
    const int c = wave * 16 + kg * 4;
    #pragma unroll
    for (int di = 0; di < 3; di++)
        #pragma unroll
        for (int r = 0; r < 4; r++)
            atomicAdd(&A[(c + r) * 48 + di * 16 + arow], acc[di][r]);
}

// -------- top-k(4 ways) sparsified softmax combine; norms computed from ssq ----------
__global__ __launch_bounds__(64) void topk_kernel(
    const float* __restrict__ attn_raw, const float* __restrict__ ssqq,
    const float* __restrict__ ssqk, const float* __restrict__ temp,
    const float* __restrict__ mix, float* __restrict__ Acomb)
{
    const int rowid = blockIdx.x;  // bh*48 + c
    const int c = rowid % 48, bh = rowid / 48, h = bh & 3, b = bh >> 2;
    const int lane = threadIdx.x;
    __shared__ float a[48];
    const float iq = (1.f / fmaxf(sqrtf(ssqq[b * 192 + h * 48 + c]), 1e-12f)) * temp[h];
    if (lane < 48) {
        const float ik = 1.f / fmaxf(sqrtf(ssqk[b * 192 + h * 48 + lane]), 1e-12f);
        a[lane] = attn_raw[(size_t)bh * 2304 + c * 48 + lane] * iq * ik;
    }
    __syncthreads();
    const float av = (lane < 48) ? a[lane] : -INFINITY;
    int cnt_gt = 0, cnt_ge = 0;
    if (lane < 48) {
        for (int j = 0; j < 48; j++) { cnt_gt += (a[j] > av); cnt_ge += (a[j] >= av); }
    }
    const float m = wmax(av);
    const float p = (lane < 48) ? expf(av - m) : 0.f;
    float coeff = 0.f;
    const int kks[4] = {24, 32, 36, 38};
    #pragma unroll
    for (int i = 0; i < 4; i++) {
        const int kk = kks[i];
        float cand = (lane < 48 && cnt_gt < kk && cnt_ge >= kk) ? av : -INFINITY;
        cand = wmax(cand);
        const bool pass = (lane < 48) && (av >= cand);
        float z = wsum(pass ? p : 0.f);
        coeff += pass ? (mix[i] / z) : 0.f;
    }
    if (lane < 48) Acomb[(size_t)bh * 2304 + c * 48 + lane] = p * coeff;
}

// ---- attnv via MFMA: OT[b][n][h*48+c] = sum_d Acomb[c][d] * V[d][n] ------------------
__global__ __launch_bounds__(256) void attnv_mfma_kernel(
    const float* __restrict__ Acomb, const bf16* __restrict__ V,
    bf16* __restrict__ OT, int N)
{
    __shared__ short As[48 * 64];     // 6144 B
    __shared__ short vs[64 * 256];    // 32768 B ; reused as ot[256][48] after compute
    const int b = blockIdx.z, h = blockIdx.y;
    const int n0 = blockIdx.x * 256;
    const int tid = threadIdx.x;
    const int wave = tid >> 6, lane = tid & 63;
    const int arow = lane & 15, kg = lane >> 4;

    const float* Ap = Acomb + (size_t)(b * 4 + h) * 2304;
    for (int i = tid; i < 3072; i += 256) {
        const int row = i >> 6, col = i & 63;
        As[i] = (col < 48) ? f2bf_bits(Ap[row * 48 + col]) : (short)0;
    }
    const bf16* Vb = V + ((size_t)b * 192 + h * 48) * N + n0;
    #pragma unroll
    for (int i = 0; i < 6; i++) {
        const int f = (wave * 6 + i) * 64 + lane;
        const int row = f >> 5, c = f & 31;
        const int cs = c ^ ((row >> 3) & 3);
        gld_lds16(Vb + (size_t)row * N + cs * 8, (char*)vs + (size_t)f * 16);
    }
    {
        short8 z = {0,0,0,0,0,0,0,0};
        for (int i = tid; i < 512; i += 256)
            *(short8*)&vs[48 * 256 + i * 8] = z;
    }
    __syncthreads();

    short8 af[3][2];
    #pragma unroll
    for (int s3 = 0; s3 < 3; s3++)
        #pragma unroll
        for (int kf = 0; kf < 2; kf++)
            af[s3][kf] = *(const short8*)&As[(s3 * 16 + arow) * 64 + kf * 32 + kg * 8];

    f32x4 acc[3][4];
    #pragma unroll
    for (int s3 = 0; s3 < 3; s3++)
        #pragma unroll
        for (int t = 0; t < 4; t++) acc[s3][t] = (f32x4){0.f, 0.f, 0.f, 0.f};

    #pragma unroll
    for (int t = 0; t < 4; t++) {
        const int nl = wave * 64 + t * 16 + arow;
        const int nlc = nl >> 3, nr = nl & 7;
        short8 bf[2];
        #pragma unroll
        for (int kf = 0; kf < 2; kf++) {
            const int cs = nlc ^ kg;
            #pragma unroll
            for (int j = 0; j < 8; j++) {
                const int d = kf * 32 + kg * 8 + j;
                ((short*)&bf[kf])[j] = vs[d * 256 + cs * 8 + nr];
            }
        }
        #pragma unroll
        for (int s3 = 0; s3 < 3; s3++) {
            acc[s3][t] = __builtin_amdgcn_mfma_f32_16x16x32_bf16(af[s3][0], bf[0], acc[s3][t], 0, 0, 0);
            acc[s3][t] = __builtin_amdgcn_mfma_f32_16x16x32_bf16(af[s3][1], bf[1], acc[s3][t], 0, 0, 0);
        }
    }
    __syncthreads();
    short* ot = vs;
    #pragma unroll
    for (int s3 = 0; s3 < 3; s3++)
        #pragma unroll
        for (int t = 0; t < 4; t++) {
            const int nl = wave * 64 + t * 16 + arow;
            #pragma unroll
            for (int r = 0; r < 4; r++)
                ot[nl * 48 + s3 * 16 + kg * 4 + r] = f2bf_bits(acc[s3][t][r]);
        }
    __syncthreads();
    for (int i = tid; i < 1536; i += 256) {
        const int row = i / 6, q = i % 6;
        *(uint4*)((char*)(OT + ((size_t)(b * 16384 + n0 + row)) * 192 + h * 48) + q * 16) =
            *(const uint4*)((const char*)&ot[row * 48] + q * 16);
    }
}

// ---------------- launch ----------------
extern "C" void kernel_launch(void* const* d_in, const int* in_sizes, int n_in,
                              void* d_out, int out_size, void* d_ws, size_t ws_size,
                              hipStream_t stream)
{
    const float* x       = (const float*)d_in[0];
    const float* y       = (const float*)d_in[1];
    const float* ln1_w   = (const float*)d_in[2];
    const float* ln1_b   = (const float*)d_in[3];
    const float* ln2_w   = (const float*)d_in[4];
    const float* ln2_b   = (const float*)d_in[5];
    const float* kv_w    = (const float*)d_in[6];
    const float* kv_dw   = (const float*)d_in[7];
    const float* q_w     = (const float*)d_in[8];
    const float* q_dw    = (const float*)d_in[9];
    const float* po_w    = (const float*)d_in[10];
    const float* temp    = (const float*)d_in[11];
    const float* mix     = (const float*)d_in[12];
    const float* ffn_in_w  = (const float*)d_in[13];
    const float* ffn_dw    = (const float*)d_in[14];
    const float* ffn_out_w = (const float*)d_in[15];
    float* out = (float*)d_out;

    const int N = 16384;
    const size_t TB = (size_t)4 * N * 192 * 2;   // 25,165,824 bytes

    char* ws = (char*)d_ws;
    bf16* XT0 = (bf16*)ws;                        // yn / xn / xn2 (T-layout [b][n][192])
    bf16* XT1 = (bf16*)(ws + TB);                 // q/k/v_pre plane; attn_outT
    bf16* Q   = (bf16*)(ws + 2 * TB);
    bf16* Kb  = (bf16*)(ws + 3 * TB);
    bf16* V   = (bf16*)(ws + 4 * TB);
    float* S  = (float*)(ws + 5 * TB);            // @ 125,829,120
    float* ssqq = S;
    float* ssqk = S + 768;
    float* attn_raw = S + 1536;
    float* Acomb = attn_raw + 16 * 48 * 48;       // S region < 310 KB
    bf16* Wq  = (bf16*)(ws + 5 * TB + 331776);
    bf16* Wkv = Wq + 36864;        // 384x192
    bf16* Wpo = Wkv + 73728;       // 192x192
    bf16* Wfi = Wpo + 36864;       // 1024x192 (1020 real + 4 zero rows)
    bf16* Wfo = Wfi + 196608;      // 192x512  (K padded 510->512)
    bf16* FB = (bf16*)(ws + TB);
    bf16* GT = (bf16*)(ws + TB + (size_t)66846720);   // ends 125,566,976 < 5*TB

    const dim3 blk(256);
    const dim3 ln_grid(4 * N / 128);
    const dim3 dwg(8, 192, 4);
    const dim3 g192(3, 128, 4);

    // ---- preconvert weights to bf16 ; zero ssq + attn accumulators ----
    wconv_kernel<<<dim3((192 * 192 + 255) / 256), blk, 0, stream>>>(q_w, Wq, 192, 192, 192, 192, 192);
    wconv_kernel<<<dim3((384 * 192 + 255) / 256), blk, 0, stream>>>(kv_w, Wkv, 384, 384, 192, 192, 192);
    wconv_kernel<<<dim3((192 * 192 + 255) / 256), blk, 0, stream>>>(po_w, Wpo, 192, 192, 192, 192, 192);
    wconv_kernel<<<dim3((1024 * 192 + 255) / 256), blk, 0, stream>>>(ffn_in_w, Wfi, 1020, 1024, 192, 192, 192);
    wconv_kernel<<<dim3((192 * 512 + 255) / 256), blk, 0, stream>>>(ffn_out_w, Wfo, 192, 192, 510, 512, 510);
    hipMemsetAsync(S, 0, (1536 + 16 * 48 * 48) * 4, stream);

    // ---- q path ----
    ln_t_kernel<<<ln_grid, blk, 0, stream>>>(y, ln1_w, ln1_b, XT0, N);
    ldsx_gemm_kernel<0><<<g192, blk, 0, stream>>>(Wq, XT0, nullptr, XT1, 192, 192, N);
    dwconv3_tile_kernel<1><<<dwg, blk, 0, stream>>>(XT1, q_dw, Q, 192, ssqq);
    // ---- k, v path ----
    ln_t_kernel<<<ln_grid, blk, 0, stream>>>(x, ln1_w, ln1_b, XT0, N);
    ldsx_gemm_kernel<0><<<g192, blk, 0, stream>>>(Wkv, XT0, nullptr, XT1, 192, 192, N);
    dwconv3_tile_kernel<1><<<dwg, blk, 0, stream>>>(XT1, kv_dw, Kb, 192, ssqk);
    ldsx_gemm_kernel<0><<<g192, blk, 0, stream>>>(Wkv + 192 * 192, XT0, nullptr, XT1, 192, 192, N);
    dwconv3_tile_kernel<0><<<dwg, blk, 0, stream>>>(XT1, kv_dw + 192 * 9, V, 192, nullptr);
    // ---- attention matrix, combine ----
    gram_mfma_kernel<<<dim3(32, 4, 4), dim3(192), 0, stream>>>(Q, Kb, attn_raw, N);
    topk_kernel<<<dim3(768), dim3(64), 0, stream>>>(attn_raw, ssqq, ssqk, temp, mix, Acomb);
    // ---- attn_out (T) -> XT1 ; x1 = x + po(attn_out) -> out ----
    attnv_mfma_kernel<<<dim3(N / 256, 4, 4), blk, 0, stream>>>(Acomb, V, XT1, N);
    ldsx_gemm_kernel<1><<<g192, blk, 0, stream>>>(Wpo, XT1, x, out, 192, 192, N);
    // ---- FFN ----
    ln_t_kernel<<<ln_grid, blk, 0, stream>>>(out, ln2_w, ln2_b, XT0, N);
    for (int bp = 0; bp < 2; bp++) {
        const bf16* X2 = XT0 + (size_t)bp * 2 * N * 192;
        float* Ybp = out + (size_t)bp * 2 * 192 * N;
        ldsx_gemm_kernel<0><<<dim3(16, 128, 2), blk, 0, stream>>>(Wfi, X2, nullptr, FB, 1020, 192, N);
        dwgelu_tile_kernel<<<dim3(16, 128, 2), blk, 0, stream>>>(FB, ffn_dw, GT);
        ldsx512_gemm_kernel<<<dim3(3, 128, 2), blk, 0, stream>>>(Wfo, GT, Ybp, Ybp, 192, 512, N);
    }
}

// Round 22
// 387.599 us; speedup vs baseline: 1.1183x; 1.1183x over previous
//
#include <hip/hip_runtime.h>
#include <hip/hip_bf16.h>

using bf16 = __hip_bfloat16;
typedef __attribute__((ext_vector_type(8))) short short8;
typedef __attribute__((ext_vector_type(4))) float f32x4;

// ---------------- helpers ----------------
__device__ __forceinline__ float tof(float v) { return v; }
__device__ __forceinline__ float tof(bf16 v) { return __bfloat162float(v); }
__device__ __forceinline__ float s2f(short s) {
    return __uint_as_float(((unsigned)(unsigned short)s) << 16);
}
__device__ __forceinline__ void storev(float* p, float v) { *p = v; }
__device__ __forceinline__ void storev(bf16* p, float v) { *p = __float2bfloat16(v); }
__device__ __forceinline__ short f2bf_bits(float v) {
    bf16 h = __float2bfloat16(v);
    return *(short*)&h;
}
__device__ __forceinline__ float wsum(float v) {
    #pragma unroll
    for (int o = 32; o > 0; o >>= 1) v += __shfl_xor(v, o);
    return v;
}
__device__ __forceinline__ float wmax(float v) {
    #pragma unroll
    for (int o = 32; o > 0; o >>= 1) v = fmaxf(v, __shfl_xor(v, o));
    return v;
}
// async global->LDS, 16B per lane; LDS dest = wave-uniform base + lane*16
__device__ __forceinline__ void gld_lds16(const void* g, void* l) {
    __builtin_amdgcn_global_load_lds(
        (const __attribute__((address_space(1))) void*)g,
        (__attribute__((address_space(3))) void*)l, 16, 0, 0);
}

// ---------------- weight preconvert: fp32 [Oreal][WLD] -> bf16 [Oalloc][KP], pad 0 ----
__global__ __launch_bounds__(256) void wconv_kernel(
    const float* __restrict__ src, bf16* __restrict__ dst,
    int Oreal, int Oalloc, int K, int KP, int WLD)
{
    const int idx = blockIdx.x * 256 + threadIdx.x;
    if (idx >= Oalloc * KP) return;
    const int o = idx / KP, k = idx % KP;
    float v = (o < Oreal && k < K) ? src[(size_t)o * WLD + k] : 0.f;
    dst[idx] = __float2bfloat16(v);
}

// ---------------- LayerNorm C=192: fp32 [b][192][N] -> bf16 [b][n][192] ----------------
__global__ __launch_bounds__(256) void ln_t_kernel(
    const float* __restrict__ X, const float* __restrict__ w,
    const float* __restrict__ bias, bf16* __restrict__ Y, int N)
{
    __shared__ short ot[128][194];   // row stride 388B: bank stride 97 == 1 (mod 32)
    const int wv = threadIdx.x >> 6, ln_ = threadIdx.x & 63;
    const int pl = wv * 32 + (ln_ & 31);
    const int pg = blockIdx.x * 128 + pl;
    const int b = pg >> 14, n = pg & 16383;       // N = 16384
    const int c0 = (ln_ >> 5) * 96;
    const float* xp = X + ((size_t)b * 192 + c0) * N + n;
    float s = 0.f, s2 = 0.f;
    #pragma unroll
    for (int c = 0; c < 96; c++) { float v = xp[(size_t)c * N]; s += v; s2 += v * v; }
    s += __shfl_xor(s, 32);
    s2 += __shfl_xor(s2, 32);
    const float mean = s * (1.f / 192.f);
    const float rstd = rsqrtf(s2 * (1.f / 192.f) - mean * mean + 1e-5f);
    #pragma unroll
    for (int c = 0; c < 96; c += 2) {
        float v0 = (xp[(size_t)c * N] - mean) * rstd * w[c0 + c] + bias[c0 + c];
        float v1 = (xp[(size_t)(c + 1) * N] - mean) * rstd * w[c0 + c + 1] + bias[c0 + c + 1];
        unsigned u = (unsigned)(unsigned short)f2bf_bits(v0) |
                     ((unsigned)(unsigned short)f2bf_bits(v1) << 16);
        *(unsigned*)&ot[pl][c0 + c] = u;
    }
    __syncthreads();
    bf16* yb = Y + (size_t)blockIdx.x * 128 * 192;
    for (int i = threadIdx.x; i < 12288; i += 256) {
        const int row = i / 96, q = i % 96;
        *(unsigned*)(yb + (size_t)row * 192 + q * 2) = *(const unsigned*)&ot[row][q * 2];
    }
}

// ---- LDS-staged MFMA GEMM, K=192: Y[b][o][n] = W[o][:].X[b][n][:] --------------------
template<int OUTF>
__global__ __launch_bounds__(256) void ldsx_gemm_kernel(
    const bf16* __restrict__ Wb, const bf16* __restrict__ X,
    const float* __restrict__ Rsd, void* __restrict__ Yv,
    int O, int KS, int NROW)
{
    __shared__ short xs[128 * 192];   // 49152 B
    const int OT = gridDim.x, NT = gridDim.y;
    const int orig = blockIdx.x + OT * (blockIdx.y + NT * blockIdx.z);
    const int total = OT * NT * gridDim.z;
    const int qq = total >> 3, rr = total & 7;
    const int xcd = orig & 7, loc = orig >> 3;
    const int nw = (xcd < rr ? xcd * (qq + 1) : rr * (qq + 1) + (xcd - rr) * qq) + loc;
    const int o0 = (nw % OT) * 64;
    const int nbase = ((nw / OT) % NT) * 128;
    const int b = nw / (OT * NT);

    const int wave = threadIdx.x >> 6, lane = threadIdx.x & 63;
    const int arow = lane & 15, kg = lane >> 4;

    const bf16* Xb = X + ((size_t)b * NROW + nbase) * KS;

    short8 wf[6];
    {
        const bf16* wp = Wb + (size_t)(o0 + wave * 16 + arow) * 192 + kg * 8;
        #pragma unroll
        for (int ks = 0; ks < 6; ks++) wf[ks] = *(const short8*)(wp + ks * 32);
    }
    #pragma unroll
    for (int i = 0; i < 12; i++) {
        const int f = (wave * 12 + i) * 64 + lane;
        const int row = f / 24, c = f % 24;
        const int cs = c ^ (row & 7);
        gld_lds16(Xb + (size_t)row * KS + cs * 8,
                  (char*)xs + (size_t)(wave * 12 + i) * 1024);
    }
    __syncthreads();

    f32x4 acc[8];
    #pragma unroll
    for (int s = 0; s < 8; s++) acc[s] = (f32x4){0.f, 0.f, 0.f, 0.f};
    #pragma unroll
    for (int s = 0; s < 8; s++) {
        const int row = s * 16 + arow;
        const char* rb = (const char*)xs + row * 384;
        #pragma unroll
        for (int ks = 0; ks < 6; ks++) {
            const int c = kg + ks * 4;
            short8 xf = *(const short8*)(rb + ((c ^ (row & 7)) << 4));
            acc[s] = __builtin_amdgcn_mfma_f32_16x16x32_bf16(wf[ks], xf, acc[s], 0, 0, 0);
        }
    }

    if constexpr (OUTF == 0) {
        __syncthreads();
        #pragma unroll
        for (int s = 0; s < 8; s++)
            #pragma unroll
            for (int r = 0; r < 4; r++)
                xs[(wave * 16 + kg * 4 + r) * 136 + s * 16 + arow] = f2bf_bits(acc[s][r]);
        __syncthreads();
        bf16* Y = (bf16*)Yv;
        for (int i = threadIdx.x; i < 1024; i += 256) {
            const int row = i >> 4, c8 = (i & 15) * 8;
            const int o = o0 + row;
            if (o < O)
                *(short8*)(Y + ((size_t)b * O + o) * NROW + nbase + c8) =
                    *(const short8*)&xs[row * 136 + c8];
        }
    } else {
        float* fo = (float*)xs;
        __syncthreads();
        #pragma unroll
        for (int s = 0; s < 8; s++)
            #pragma unroll
            for (int r = 0; r < 4; r++)
                fo[(wave * 16 + kg * 4 + r) * 132 + s * 16 + arow] = acc[s][r];
        __syncthreads();
        float* Y = (float*)Yv;
        for (int i = threadIdx.x; i < 8192; i += 256) {
            const int row = i >> 7, col = i & 127;
            const size_t off = ((size_t)b * O + o0 + row) * NROW + nbase + col;
            Y[off] = fo[row * 132 + col] + Rsd[off];
        }
    }
}

// ---- K=512 GEMM (ffn_out): gld_lds staging, per-chunk W regs (no spill) --------------
__global__ __launch_bounds__(256) void ldsx512_gemm_kernel(
    const bf16* __restrict__ Wb, const bf16* __restrict__ X,
    const float* __restrict__ Rsd, float* __restrict__ Y,
    int O, int KS, int NROW)
{
    __shared__ char smem[33792];      // staging: 32768B shorts; epilogue: float[64][132]
    short* xs = (short*)smem;
    float* fo = (float*)smem;
    const int OT = gridDim.x, NT = gridDim.y;
    const int orig = blockIdx.x + OT * (blockIdx.y + NT * blockIdx.z);
    const int total = OT * NT * gridDim.z;
    const int qq = total >> 3, rr = total & 7;
    const int xcd = orig & 7, loc = orig >> 3;
    const int nw = (xcd < rr ? xcd * (qq + 1) : rr * (qq + 1) + (xcd - rr) * qq) + loc;
    const int o0 = (nw % OT) * 64;
    const int nbase = ((nw / OT) % NT) * 128;
    const int b = nw / (OT * NT);

    const int wave = threadIdx.x >> 6, lane = threadIdx.x & 63;
    const int arow = lane & 15, kg = lane >> 4;

    const bf16* Wp = Wb + (size_t)(o0 + wave * 16 + arow) * 512 + kg * 8;
    const bf16* Xb = X + ((size_t)b * NROW + nbase) * KS;

    f32x4 acc[8];
    #pragma unroll
    for (int s = 0; s < 8; s++) acc[s] = (f32x4){0.f, 0.f, 0.f, 0.f};

    #pragma unroll 1
    for (int kt = 0; kt < 4; kt++) {
        if (kt) __syncthreads();
        #pragma unroll
        for (int i = 0; i < 8; i++) {
            const int f = (wave * 8 + i) * 64 + lane;
            const int row = f >> 4, c = f & 15;
            const int cs = c ^ (row & 7);
            gld_lds16(Xb + (size_t)row * KS + kt * 128 + cs * 8,
                      (char*)xs + (size_t)(wave * 8 + i) * 1024);
        }
        // W chunk for this kt (L2-resident), 16 VGPRs only
        short8 wf4[4];
        #pragma unroll
        for (int ks = 0; ks < 4; ks++) wf4[ks] = *(const short8*)(Wp + kt * 128 + ks * 32);
        __syncthreads();
        #pragma unroll
        for (int s = 0; s < 8; s++) {
            const int row = s * 16 + arow;
            const char* rb = (const char*)xs + row * 256;
            #pragma unroll
            for (int ks = 0; ks < 4; ks++) {
                const int c = kg + ks * 4;
                short8 xf = *(const short8*)(rb + ((c ^ (row & 7)) << 4));
                acc[s] = __builtin_amdgcn_mfma_f32_16x16x32_bf16(wf4[ks], xf, acc[s], 0, 0, 0);
            }
        }
    }
    __syncthreads();
    #pragma unroll
    for (int s = 0; s < 8; s++)
        #pragma unroll
        for (int r = 0; r < 4; r++)
            fo[(wave * 16 + kg * 4 + r) * 132 + s * 16 + arow] = acc[s][r];
    __syncthreads();
    for (int i = threadIdx.x; i < 8192; i += 256) {
        const int row = i >> 7, col = i & 127;
        const size_t off = ((size_t)b * O + o0 + row) * NROW + nbase + col;
        Y[off] = fo[row * 132 + col] + Rsd[off];
    }
}

// -------- tiled depthwise 3x3 (bf16 planes); SSQ: fused sum-of-squares accumulation ---
template<int SSQ>
__global__ __launch_bounds__(256) void dwconv3_tile_kernel(
    const bf16* __restrict__ X, const float* __restrict__ Wd, bf16* __restrict__ Y,
    int CH, float* __restrict__ ssq)
{
    __shared__ short sm[18][144];   // x0 at col 8; zero halos at 7 and 136
    const int b = blockIdx.z, ch = blockIdx.y;
    const int y0 = blockIdx.x * 16;
    const int tid = threadIdx.x;
    const size_t base = ((size_t)b * CH + ch) * 16384;

    for (int idx = tid; idx < 288; idx += 256) {
        const int r = idx >> 4, xc = idx & 15;
        const int yy = y0 - 1 + r;
        short8 v = {0, 0, 0, 0, 0, 0, 0, 0};
        if (yy >= 0 && yy < 128) v = *(const short8*)(X + base + yy * 128 + xc * 8);
        *(short8*)&sm[r][8 + xc * 8] = v;
    }
    if (tid < 18) { sm[tid][7] = 0; sm[tid][136] = 0; }
    __syncthreads();

    float wv[9];
    #pragma unroll
    for (int i = 0; i < 9; i++) wv[i] = Wd[ch * 9 + i];

    const int ty = tid >> 4, xg = tid & 15;
    float a[8] = {0.f, 0.f, 0.f, 0.f, 0.f, 0.f, 0.f, 0.f};
    #pragma unroll
    for (int dy = 0; dy < 3; dy++) {
        const short* row = &sm[ty + dy][xg * 8];
        short8 pv = *(const short8*)row;
        short8 cv = *(const short8*)(row + 8);
        short8 nv = *(const short8*)(row + 16);
        float u[10];
        u[0] = s2f(((short*)&pv)[7]);
        #pragma unroll
        for (int j = 0; j < 8; j++) u[j + 1] = s2f(((short*)&cv)[j]);
        u[9] = s2f(((short*)&nv)[0]);
        const float wa = wv[dy * 3], wb = wv[dy * 3 + 1], wc = wv[dy * 3 + 2];
        #pragma unroll
        for (int j = 0; j < 8; j++) a[j] += wa * u[j] + wb * u[j + 1] + wc * u[j + 2];
    }
    short8 ov;
    #pragma unroll
    for (int j = 0; j < 8; j++) ((short*)&ov)[j] = f2bf_bits(a[j]);
    *(short8*)(Y + base + (size_t)(y0 + ty) * 128 + xg * 8) = ov;

    if constexpr (SSQ) {
        float s = 0.f;
        #pragma unroll
        for (int j = 0; j < 8; j++) s += a[j] * a[j];
        s = wsum(s);
        __shared__ float red[4];
        if ((tid & 63) == 0) red[tid >> 6] = s;
        __syncthreads();
        if (tid == 0)
            atomicAdd(&ssq[b * 192 + ch], red[0] + red[1] + red[2] + red[3]);
    }
}

// ---- tiled fused dw3(f1)->gelu * dw3(f2) -> GT[b][n][512] ; 4 hc x 8 y x 128 x ------
__global__ __launch_bounds__(256) void dwgelu_tile_kernel(
    const bf16* __restrict__ FB, const float* __restrict__ Wd, bf16* __restrict__ GT)
{
    __shared__ short s1[4][10][152];
    __shared__ short s2[4][10][152];
    const int b = blockIdx.z;
    const int y0 = blockIdx.x * 8;
    const int hc0 = blockIdx.y * 4;
    const int tid = threadIdx.x;

    for (int idx = tid; idx < 640; idx += 256) {
        const int c = idx / 160, rem = idx % 160;
        const int r = rem >> 4, xc = rem & 15;
        const int yy = y0 - 1 + r;
        const int hc = hc0 + c;
        short8 v1 = {0,0,0,0,0,0,0,0}, v2 = v1;
        if (hc < 510 && yy >= 0 && yy < 128) {
            const size_t sp = (size_t)yy * 128 + xc * 8;
            v1 = *(const short8*)(FB + ((size_t)b * 1020 + hc) * 16384 + sp);
            v2 = *(const short8*)(FB + ((size_t)b * 1020 + 510 + hc) * 16384 + sp);
        }
        *(short8*)&s1[c][r][8 + xc * 8] = v1;
        *(short8*)&s2[c][r][8 + xc * 8] = v2;
    }
    if (tid < 40) {
        const int c = tid / 10, r = tid % 10;
        s1[c][r][7] = 0; s1[c][r][136] = 0;
        s2[c][r][7] = 0; s2[c][r][136] = 0;
    }
    __syncthreads();

    const int c = tid >> 6, y2 = (tid >> 4) & 3, xg = tid & 15;
    const int hc = hc0 + c;
    float w1[9], w2[9];
    #pragma unroll
    for (int i = 0; i < 9; i++) {
        w1[i] = (hc < 510) ? Wd[(size_t)hc * 9 + i] : 0.f;
        w2[i] = (hc < 510) ? Wd[(size_t)(510 + hc) * 9 + i] : 0.f;
    }
    float u[4][10], v[4][10];
    #pragma unroll
    for (int r = 0; r < 4; r++) {
        const short* r1 = &s1[c][y2 * 2 + r][xg * 8];
        const short* r2 = &s2[c][y2 * 2 + r][xg * 8];
        short8 pa = *(const short8*)r1;
        short8 ca = *(const short8*)(r1 + 8);
        short8 na = *(const short8*)(r1 + 16);
        short8 pb = *(const short8*)r2;
        short8 cb = *(const short8*)(r2 + 8);
        short8 nb = *(const short8*)(r2 + 16);
        u[r][0] = s2f(((short*)&pa)[7]);
        v[r][0] = s2f(((short*)&pb)[7]);
        #pragma unroll
        for (int j = 0; j < 8; j++) {
            u[r][j + 1] = s2f(((short*)&ca)[j]);
            v[r][j + 1] = s2f(((short*)&cb)[j]);
        }
        u[r][9] = s2f(((short*)&na)[0]);
        v[r][9] = s2f(((short*)&nb)[0]);
    }
    short8 ovr[2];
    #pragma unroll
    for (int t = 0; t < 2; t++) {
        float d1[8] = {0.f,0.f,0.f,0.f,0.f,0.f,0.f,0.f};
        float d2[8] = {0.f,0.f,0.f,0.f,0.f,0.f,0.f,0.f};
        #pragma unroll
        for (int dy = 0; dy < 3; dy++) {
            const int r = t + dy;
            const float a0 = w1[dy * 3], a1 = w1[dy * 3 + 1], a2 = w1[dy * 3 + 2];
            const float b0 = w2[dy * 3], b1 = w2[dy * 3 + 1], b2 = w2[dy * 3 + 2];
            #pragma unroll
            for (int j = 0; j < 8; j++) {
                d1[j] += a0 * u[r][j] + a1 * u[r][j + 1] + a2 * u[r][j + 2];
                d2[j] += b0 * v[r][j] + b1 * v[r][j + 1] + b2 * v[r][j + 2];
            }
        }
        #pragma unroll
        for (int j = 0; j < 8; j++) {
            const float x = d1[j];
            const float z2 = 1.5957691216057308f * (x + 0.044715f * x * x * x);
            const float g = x / (1.f + __expf(-z2));
            ((short*)&ovr[t])[j] = f2bf_bits(g * d2[j]);
        }
    }
    __syncthreads();                 // all s1/s2 reads done; reuse s1 as ot[4][8][136]
    short* ot = &s1[0][0][0];
    {
        const int ob = (c * 8 + y2 * 2) * 136 + xg * 8;
        *(short8*)&ot[ob] = ovr[0];
        *(short8*)&ot[ob + 136] = ovr[1];
    }
    __syncthreads();
    for (int idx = tid; idx < 1024; idx += 256) {
        const int row = idx >> 7, col = idx & 127;
        short v0 = ot[(0 * 8 + row) * 136 + col], v1 = ot[(1 * 8 + row) * 136 + col];
        short v2 = ot[(2 * 8 + row) * 136 + col], v3 = ot[(3 * 8 + row) * 136 + col];
        uint2 pk;
        pk.x = (unsigned)(unsigned short)v0 | ((unsigned)(unsigned short)v1 << 16);
        pk.y = (unsigned)(unsigned short)v2 | ((unsigned)(unsigned short)v3 << 16);
        *(uint2*)(GT + ((size_t)b * 16384 + y0 * 128 + idx) * 512 + hc0) = pk;
    }
}

// ------- gram via MFMA: attn_raw[bh][c][d] += sum_n q[c,n]*k[d,n] over n-chunk --------
__global__ __launch_bounds__(192) void gram_mfma_kernel(
    const bf16* __restrict__ Q, const bf16* __restrict__ K,
    float* __restrict__ attn_raw, int N)
{
    const int b = blockIdx.z, h = blockIdx.y;
    const int n0base = blockIdx.x * 512;
    const int wave = threadIdx.x >> 6, lane = threadIdx.x & 63;
    const int arow = lane & 15, kg = lane >> 4;
    const bf16* Qb = Q + ((size_t)b * 192 + h * 48 + wave * 16 + arow) * N;
    const bf16* Kb = K + ((size_t)b * 192 + h * 48) * N;

    f32x4 acc[3];
    #pragma unroll
    for (int di = 0; di < 3; di++) acc[di] = (f32x4){0.f, 0.f, 0.f, 0.f};

    #pragma unroll 4
    for (int t = 0; t < 16; t++) {
        const int n0 = n0base + t * 32 + kg * 8;
        short8 a = *(const short8*)(Qb + n0);
        #pragma unroll
        for (int di = 0; di < 3; di++) {
            short8 bfr = *(const short8*)(Kb + (size_t)(di * 16 + arow) * N + n0);
            acc[di] = __builtin_amdgcn_mfma_f32_16x16x32_bf16(a, bfr, acc[di], 0, 0, 0);
        }
    }
    float* A = attn_raw + (size_t)(b * 4 + h) * 2304;
    const int c = wave * 16 + kg * 4;
    #pragma unroll
    for (int di = 0; di < 3; di++)
        #pragma unroll
        for (int r = 0; r < 4; r++)
            atomicAdd(&A[(c + r) * 48 + di * 16 + arow], acc[di][r]);
}

// -------- top-k(4 ways) sparsified softmax combine; norms computed from ssq ----------
__global__ __launch_bounds__(64) void topk_kernel(
    const float* __restrict__ attn_raw, const float* __restrict__ ssqq,
    const float* __restrict__ ssqk, const float* __restrict__ temp,
    const float* __restrict__ mix, float* __restrict__ Acomb)
{
    const int rowid = blockIdx.x;  // bh*48 + c
    const int c = rowid % 48, bh = rowid / 48, h = bh & 3, b = bh >> 2;
    const int lane = threadIdx.x;
    __shared__ float a[48];
    const float iq = (1.f / fmaxf(sqrtf(ssqq[b * 192 + h * 48 + c]), 1e-12f)) * temp[h];
    if (lane < 48) {
        const float ik = 1.f / fmaxf(sqrtf(ssqk[b * 192 + h * 48 + lane]), 1e-12f);
        a[lane] = attn_raw[(size_t)bh * 2304 + c * 48 + lane] * iq * ik;
    }
    __syncthreads();
    const float av = (lane < 48) ? a[lane] : -INFINITY;
    int cnt_gt = 0, cnt_ge = 0;
    if (lane < 48) {
        for (int j = 0; j < 48; j++) { cnt_gt += (a[j] > av); cnt_ge += (a[j] >= av); }
    }
    const float m = wmax(av);
    const float p = (lane < 48) ? expf(av - m) : 0.f;
    float coeff = 0.f;
    const int kks[4] = {24, 32, 36, 38};
    #pragma unroll
    for (int i = 0; i < 4; i++) {
        const int kk = kks[i];
        float cand = (lane < 48 && cnt_gt < kk && cnt_ge >= kk) ? av : -INFINITY;
        cand = wmax(cand);
        const bool pass = (lane < 48) && (av >= cand);
        float z = wsum(pass ? p : 0.f);
        coeff += pass ? (mix[i] / z) : 0.f;
    }
    if (lane < 48) Acomb[(size_t)bh * 2304 + c * 48 + lane] = p * coeff;
}

// ---- attnv via MFMA: OT[b][n][h*48+c] = sum_d Acomb[c][d] * V[d][n] ------------------
__global__ __launch_bounds__(256) void attnv_mfma_kernel(
    const float* __restrict__ Acomb, const bf16* __restrict__ V,
    bf16* __restrict__ OT, int N)
{
    __shared__ short As[48 * 64];     // 6144 B
    __shared__ short vs[64 * 256];    // 32768 B ; reused as ot[256][48] after compute
    const int b = blockIdx.z, h = blockIdx.y;
    const int n0 = blockIdx.x * 256;
    const int tid = threadIdx.x;
    const int wave = tid >> 6, lane = tid & 63;
    const int arow = lane & 15, kg = lane >> 4;

    const float* Ap = Acomb + (size_t)(b * 4 + h) * 2304;
    for (int i = tid; i < 3072; i += 256) {
        const int row = i >> 6, col = i & 63;
        As[i] = (col < 48) ? f2bf_bits(Ap[row * 48 + col]) : (short)0;
    }
    const bf16* Vb = V + ((size_t)b * 192 + h * 48) * N + n0;
    #pragma unroll
    for (int i = 0; i < 6; i++) {
        const int f = (wave * 6 + i) * 64 + lane;
        const int row = f >> 5, c = f & 31;
        const int cs = c ^ ((row >> 3) & 3);
        gld_lds16(Vb + (size_t)row * N + cs * 8, (char*)vs + (size_t)f * 16);
    }
    {
        short8 z = {0,0,0,0,0,0,0,0};
        for (int i = tid; i < 512; i += 256)
            *(short8*)&vs[48 * 256 + i * 8] = z;
    }
    __syncthreads();

    short8 af[3][2];
    #pragma unroll
    for (int s3 = 0; s3 < 3; s3++)
        #pragma unroll
        for (int kf = 0; kf < 2; kf++)
            af[s3][kf] = *(const short8*)&As[(s3 * 16 + arow) * 64 + kf * 32 + kg * 8];

    f32x4 acc[3][4];
    #pragma unroll
    for (int s3 = 0; s3 < 3; s3++)
        #pragma unroll
        for (int t = 0; t < 4; t++) acc[s3][t] = (f32x4){0.f, 0.f, 0.f, 0.f};

    #pragma unroll
    for (int t = 0; t < 4; t++) {
        const int nl = wave * 64 + t * 16 + arow;
        const int nlc = nl >> 3, nr = nl & 7;
        short8 bf[2];
        #pragma unroll
        for (int kf = 0; kf < 2; kf++) {
            const int cs = nlc ^ kg;
            #pragma unroll
            for (int j = 0; j < 8; j++) {
                const int d = kf * 32 + kg * 8 + j;
                ((short*)&bf[kf])[j] = vs[d * 256 + cs * 8 + nr];
            }
        }
        #pragma unroll
        for (int s3 = 0; s3 < 3; s3++) {
            acc[s3][t] = __builtin_amdgcn_mfma_f32_16x16x32_bf16(af[s3][0], bf[0], acc[s3][t], 0, 0, 0);
            acc[s3][t] = __builtin_amdgcn_mfma_f32_16x16x32_bf16(af[s3][1], bf[1], acc[s3][t], 0, 0, 0);
        }
    }
    __syncthreads();
    short* ot = vs;
    #pragma unroll
    for (int s3 = 0; s3 < 3; s3++)
        #pragma unroll
        for (int t = 0; t < 4; t++) {
            const int nl = wave * 64 + t * 16 + arow;
            #pragma unroll
            for (int r = 0; r < 4; r++)
                ot[nl * 48 + s3 * 16 + kg * 4 + r] = f2bf_bits(acc[s3][t][r]);
        }
    __syncthreads();
    for (int i = tid; i < 1536; i += 256) {
        const int row = i / 6, q = i % 6;
        *(uint4*)((char*)(OT + ((size_t)(b * 16384 + n0 + row)) * 192 + h * 48) + q * 16) =
            *(const uint4*)((const char*)&ot[row * 48] + q * 16);
    }
}

// ---------------- launch ----------------
extern "C" void kernel_launch(void* const* d_in, const int* in_sizes, int n_in,
                              void* d_out, int out_size, void* d_ws, size_t ws_size,
                              hipStream_t stream)
{
    const float* x       = (const float*)d_in[0];
    const float* y       = (const float*)d_in[1];
    const float* ln1_w   = (const float*)d_in[2];
    const float* ln1_b   = (const float*)d_in[3];
    const float* ln2_w   = (const float*)d_in[4];
    const float* ln2_b   = (const float*)d_in[5];
    const float* kv_w    = (const float*)d_in[6];
    const float* kv_dw   = (const float*)d_in[7];
    const float* q_w     = (const float*)d_in[8];
    const float* q_dw    = (const float*)d_in[9];
    const float* po_w    = (const float*)d_in[10];
    const float* temp    = (const float*)d_in[11];
    const float* mix     = (const float*)d_in[12];
    const float* ffn_in_w  = (const float*)d_in[13];
    const float* ffn_dw    = (const float*)d_in[14];
    const float* ffn_out_w = (const float*)d_in[15];
    float* out = (float*)d_out;

    const int N = 16384;
    const size_t TB = (size_t)4 * N * 192 * 2;   // 25,165,824 bytes

    char* ws = (char*)d_ws;
    bf16* XT0 = (bf16*)ws;                        // yn / xn / xn2 (T-layout [b][n][192])
    bf16* XT1 = (bf16*)(ws + TB);                 // q/k/v_pre plane; attn_outT
    bf16* Q   = (bf16*)(ws + 2 * TB);
    bf16* Kb  = (bf16*)(ws + 3 * TB);
    bf16* V   = (bf16*)(ws + 4 * TB);
    float* S  = (float*)(ws + 5 * TB);            // @ 125,829,120
    float* ssqq = S;
    float* ssqk = S + 768;
    float* attn_raw = S + 1536;
    float* Acomb = attn_raw + 16 * 48 * 48;       // S region < 310 KB
    bf16* Wq  = (bf16*)(ws + 5 * TB + 331776);
    bf16* Wkv = Wq + 36864;        // 384x192
    bf16* Wpo = Wkv + 73728;       // 192x192
    bf16* Wfi = Wpo + 36864;       // 1024x192 (1020 real + 4 zero rows)
    bf16* Wfo = Wfi + 196608;      // 192x512  (K padded 510->512)
    bf16* FB = (bf16*)(ws + TB);
    bf16* GT = (bf16*)(ws + TB + (size_t)66846720);   // ends 125,566,976 < 5*TB

    const dim3 blk(256);
    const dim3 ln_grid(4 * N / 128);
    const dim3 dwg(8, 192, 4);
    const dim3 g192(3, 128, 4);

    // ---- preconvert weights to bf16 ; zero ssq + attn accumulators ----
    wconv_kernel<<<dim3((192 * 192 + 255) / 256), blk, 0, stream>>>(q_w, Wq, 192, 192, 192, 192, 192);
    wconv_kernel<<<dim3((384 * 192 + 255) / 256), blk, 0, stream>>>(kv_w, Wkv, 384, 384, 192, 192, 192);
    wconv_kernel<<<dim3((192 * 192 + 255) / 256), blk, 0, stream>>>(po_w, Wpo, 192, 192, 192, 192, 192);
    wconv_kernel<<<dim3((1024 * 192 + 255) / 256), blk, 0, stream>>>(ffn_in_w, Wfi, 1020, 1024, 192, 192, 192);
    wconv_kernel<<<dim3((192 * 512 + 255) / 256), blk, 0, stream>>>(ffn_out_w, Wfo, 192, 192, 510, 512, 510);
    hipMemsetAsync(S, 0, (1536 + 16 * 48 * 48) * 4, stream);

    // ---- q path ----
    ln_t_kernel<<<ln_grid, blk, 0, stream>>>(y, ln1_w, ln1_b, XT0, N);
    ldsx_gemm_kernel<0><<<g192, blk, 0, stream>>>(Wq, XT0, nullptr, XT1, 192, 192, N);
    dwconv3_tile_kernel<1><<<dwg, blk, 0, stream>>>(XT1, q_dw, Q, 192, ssqq);
    // ---- k, v path ----
    ln_t_kernel<<<ln_grid, blk, 0, stream>>>(x, ln1_w, ln1_b, XT0, N);
    ldsx_gemm_kernel<0><<<g192, blk, 0, stream>>>(Wkv, XT0, nullptr, XT1, 192, 192, N);
    dwconv3_tile_kernel<1><<<dwg, blk, 0, stream>>>(XT1, kv_dw, Kb, 192, ssqk);
    ldsx_gemm_kernel<0><<<g192, blk, 0, stream>>>(Wkv + 192 * 192, XT0, nullptr, XT1, 192, 192, N);
    dwconv3_tile_kernel<0><<<dwg, blk, 0, stream>>>(XT1, kv_dw + 192 * 9, V, 192, nullptr);
    // ---- attention matrix, combine ----
    gram_mfma_kernel<<<dim3(32, 4, 4), dim3(192), 0, stream>>>(Q, Kb, attn_raw, N);
    topk_kernel<<<dim3(768), dim3(64), 0, stream>>>(attn_raw, ssqq, ssqk, temp, mix, Acomb);
    // ---- attn_out (T) -> XT1 ; x1 = x + po(attn_out) -> out ----
    attnv_mfma_kernel<<<dim3(N / 256, 4, 4), blk, 0, stream>>>(Acomb, V, XT1, N);
    ldsx_gemm_kernel<1><<<g192, blk, 0, stream>>>(Wpo, XT1, x, out, 192, 192, N);
    // ---- FFN ----
    ln_t_kernel<<<ln_grid, blk, 0, stream>>>(out, ln2_w, ln2_b, XT0, N);
    for (int bp = 0; bp < 2; bp++) {
        const bf16* X2 = XT0 + (size_t)bp * 2 * N * 192;
        float* Ybp = out + (size_t)bp * 2 * 192 * N;
        ldsx_gemm_kernel<0><<<dim3(16, 128, 2), blk, 0, stream>>>(Wfi, X2, nullptr, FB, 1020, 192, N);
        dwgelu_tile_kernel<<<dim3(16, 128, 2), blk, 0, stream>>>(FB, ffn_dw, GT);
        ldsx512_gemm_kernel<<<dim3(3, 128, 2), blk, 0, stream>>>(Wfo, GT, Ybp, Ybp, 192, 512, N);
    }
}